// Round 1
// baseline (68.683 us; speedup 1.0000x reference)
//
#include <hip/hip_runtime.h>

#define NB 32
#define TLEN 480000
#define SEG 1024
#define HOP 256
#define PADL 512
#define NF 1876                          // (480000+1024-1024)/256 + 1
#define FCHUNK 16
#define CHUNK_SAMP (FCHUNK*HOP + (SEG - HOP))   // 4864
#define NCHUNK ((NF + FCHUNK - 1)/FCHUNK)       // 118
#define WTHREADS 256

// ---------------- kernel 1: per-frame windowed partial sums + row sums ----
__global__ __launch_bounds__(WTHREADS) void seg_partials(
    const float* __restrict__ est, const float* __restrict__ tgt,
    float* __restrict__ ws_part, float* __restrict__ ws_bs)
{
    const int c = blockIdx.x;            // chunk of 16 frames
    const int b = blockIdx.y;            // batch row
    __shared__ float se[CHUNK_SAMP];
    __shared__ float st_[CHUNK_SAMP];
    __shared__ float redbuf[8];

    const int tid  = threadIdx.x;
    const int lane = tid & 63;
    const int wave = tid >> 6;

    const float* erow = est + (size_t)b * TLEN;
    const float* trow = tgt + (size_t)b * TLEN;
    const int jbase = c * (FCHUNK * HOP) - PADL;   // padded-coord start (orig idx)

    // per-lane squared Hann window for positions lane + 64k (covers 0..1023)
    float w2r[16];
#pragma unroll
    for (int k = 0; k < 16; ++k) {
        int p = lane + 64 * k;
        float w = 0.5f * (1.0f - cosf(6.28318530717958647692f * (float)p * (1.0f/1024.0f)));
        w2r[k] = w * w;
    }

    if (jbase >= 0 && jbase + CHUNK_SAMP <= TLEN) {
        // interior chunk: vectorized float4 staging (aligned: jbase % 16 == 0)
        const float4* e4 = (const float4*)(erow + jbase);
        const float4* t4 = (const float4*)(trow + jbase);
        float4* se4 = (float4*)se;
        float4* st4 = (float4*)st_;
        for (int v = tid; v < CHUNK_SAMP / 4; v += WTHREADS) {
            se4[v] = e4[v];
            st4[v] = t4[v];
        }
    } else {
        // edge chunk: scalar loads with reflect mapping
        for (int v = tid; v < CHUNK_SAMP; v += WTHREADS) {
            int j = jbase + v;
            int idx = (j < 0) ? -j : ((j >= TLEN) ? 2 * (TLEN - 1) - j : j);
            se[v]  = erow[idx];
            st_[v] = trow[idx];
        }
    }
    __syncthreads();

    // ---- deterministic row-sum contribution (owned, non-halo samples) ----
    int owned = TLEN - c * (FCHUNK * HOP);
    if (owned > FCHUNK * HOP) owned = FCHUNK * HOP;       // 4096 (last: 768)
    float pe = 0.f, pt = 0.f;
    for (int v = PADL + tid; v < PADL + owned; v += WTHREADS) {
        pe += se[v];
        pt += st_[v];
    }
#pragma unroll
    for (int d = 1; d < 64; d <<= 1) {
        pe += __shfl_xor(pe, d);
        pt += __shfl_xor(pt, d);
    }
    if (lane == 0) { redbuf[wave] = pe; redbuf[4 + wave] = pt; }
    __syncthreads();
    if (tid == 0) {
        float s0 = redbuf[0] + redbuf[1] + redbuf[2] + redbuf[3];
        float s1 = redbuf[4] + redbuf[5] + redbuf[6] + redbuf[7];
        ws_bs[(0 * NB + b) * NCHUNK + c] = s0;   // estimate row partial
        ws_bs[(1 * NB + b) * NCHUNK + c] = s1;   // target row partial
    }

    // ---- per-frame five windowed sums: one frame per wave, round-robin ----
    int nf_in = NF - c * FCHUNK;
    if (nf_in > FCHUNK) nf_in = FCHUNK;
    for (int fl = wave; fl < nf_in; fl += 4) {
        const int off = fl * HOP;
        float s_et = 0.f, s_tt = 0.f, s_ee = 0.f, s_e = 0.f, s_t = 0.f;
#pragma unroll
        for (int k = 0; k < 16; ++k) {
            float e  = se [off + lane + 64 * k];
            float t  = st_[off + lane + 64 * k];
            float w2 = w2r[k];
            float we = w2 * e;
            float wt = w2 * t;
            s_et = fmaf(we, t, s_et);
            s_tt = fmaf(wt, t, s_tt);
            s_ee = fmaf(we, e, s_ee);
            s_e += we;
            s_t += wt;
        }
#pragma unroll
        for (int d = 1; d < 64; d <<= 1) {
            s_et += __shfl_xor(s_et, d);
            s_tt += __shfl_xor(s_tt, d);
            s_ee += __shfl_xor(s_ee, d);
            s_e  += __shfl_xor(s_e,  d);
            s_t  += __shfl_xor(s_t,  d);
        }
        if (lane == 0) {
            int f = c * FCHUNK + fl;
            float* p = ws_part + (size_t)(b * NF + f) * 5;
            p[0] = s_et; p[1] = s_tt; p[2] = s_ee; p[3] = s_e; p[4] = s_t;
        }
    }
}

// ---------------- kernel 2: reduce chunk sums -> per-row means ------------
__global__ void seg_means(const float* __restrict__ ws_bs, float* __restrict__ ws_mean)
{
    int t = threadIdx.x;                 // 0..63 -> (signal, row)
    if (t < 2 * NB) {
        const float* p = ws_bs + t * NCHUNK;
        float s = 0.f;
        for (int c = 0; c < NCHUNK; ++c) s += p[c];
        ws_mean[t] = s * (1.0f / (float)TLEN);
    }
}

// ---------------- kernel 3: combine partials + means -> loss --------------
__global__ __launch_bounds__(WTHREADS) void seg_final(
    const float* __restrict__ ws_part, const float* __restrict__ ws_mean,
    float* __restrict__ out)
{
    int idx = blockIdx.x * WTHREADS + threadIdx.x;
    if (idx >= NB * NF) return;
    int b = idx / NF;
    const float* p = ws_part + (size_t)idx * 5;
    float me = ws_mean[b];
    float mt = ws_mean[NB + b];
    float S_et = p[0], S_tt = p[1], S_ee = p[2], S_e = p[3], S_t = p[4];
    const float W2 = 384.0f;             // sum of squared periodic Hann, exact

    float dot = S_et - mt * S_e - me * S_t + me * mt * W2;
    float tt  = S_tt - 2.0f * mt * S_t + mt * mt * W2;
    float ee  = S_ee - 2.0f * me * S_e + me * me * W2;

    float a    = dot / (tt + 1e-8f);
    float st2  = a * a * tt;
    float en2  = ee - 2.0f * a * dot + st2;
    float ratio = st2 / (en2 + 1e-8f);
    out[idx] = -10.0f * log10f(ratio + 1e-8f);
}

extern "C" void kernel_launch(void* const* d_in, const int* in_sizes, int n_in,
                              void* d_out, int out_size, void* d_ws, size_t ws_size,
                              hipStream_t stream)
{
    const float* est = (const float*)d_in[0];
    const float* tgt = (const float*)d_in[1];
    float* out = (float*)d_out;

    float* ws      = (float*)d_ws;
    float* ws_part = ws;                                   // NB*NF*5      floats
    float* ws_bs   = ws_part + (size_t)NB * NF * 5;        // 2*NB*NCHUNK  floats
    float* ws_mean = ws_bs + 2 * NB * NCHUNK;              // 2*NB         floats

    dim3 grid1(NCHUNK, NB);
    seg_partials<<<grid1, WTHREADS, 0, stream>>>(est, tgt, ws_part, ws_bs);
    seg_means<<<1, 64, 0, stream>>>(ws_bs, ws_mean);
    dim3 grid3((NB * NF + WTHREADS - 1) / WTHREADS);
    seg_final<<<grid3, WTHREADS, 0, stream>>>(ws_part, ws_mean, out);
}

// Round 3
// 54.393 us; speedup vs baseline: 1.2627x; 1.2627x over previous
//
#include <hip/hip_runtime.h>

#define NB 32
#define TLEN 480000
#define NF 1876                    // (480000 + 2*512 - 1024)/256 + 1
#define FR 8                       // frames per wave
#define WPR 235                    // ceil(NF/FR) waves per row
#define WTHREADS 256

// ---- DPP-based wave reduction: 4 VALU dpp-adds + 2 cross-row shuffles ----
template <int CTRL>
__device__ __forceinline__ float dpp_add(float x) {
    int y = __builtin_amdgcn_update_dpp(0, __float_as_int(x), CTRL, 0xF, 0xF, true);
    return x + __int_as_float(y);
}

__device__ __forceinline__ float wave_reduce(float s) {
    s = dpp_add<0xB1>(s);   // quad_perm(1,0,3,2) : xor1
    s = dpp_add<0x4E>(s);   // quad_perm(2,3,0,1) : xor2
    s = dpp_add<0x124>(s);  // row_ror:4
    s = dpp_add<0x128>(s);  // row_ror:8  -> all 16 lanes of each row have row sum
    s += __shfl_xor(s, 16);
    s += __shfl_xor(s, 32);
    return s;
}

__device__ __forceinline__ float f4c(const float4& v, int j) {
    return j == 0 ? v.x : (j == 1 ? v.y : (j == 2 ? v.z : v.w));
}

// ---------------- kernel 1: per-frame windowed sums, no LDS ---------------
__global__ __launch_bounds__(WTHREADS) void seg_frames(
    const float* __restrict__ est, const float* __restrict__ tgt,
    float* __restrict__ ws_part, float* __restrict__ ws_bs)
{
    const int tid  = threadIdx.x;
    const int lane = tid & 63;
    const int wave = tid >> 6;
    const int b    = blockIdx.y;
    const int wv   = blockIdx.x * 4 + wave;
    if (wv >= WPR) return;
    const int fbase = wv * FR;
    const int nfr   = (NF - fbase < FR) ? (NF - fbase) : FR;

    const float* erow = est + (size_t)b * TLEN;
    const float* trow = tgt + (size_t)b * TLEN;

    // w^2 at frame positions p = 256k + 4*lane + j   (computed once, reused 8x)
    float w2v[4][4];
#pragma unroll
    for (int k = 0; k < 4; ++k)
#pragma unroll
        for (int j = 0; j < 4; ++j) {
            float p = (float)(256 * k + 4 * lane + j);
            float w = 0.5f - 0.5f * cosf(6.28318530717958647692f * p * (1.0f / 1024.0f));
            w2v[k][j] = w * w;
        }

    float pe = 0.f, pt = 0.f;   // plain sums over owned hops (for the means)

    if (fbase >= 2 && fbase + FR - 1 <= 1872 && nfr == FR) {
        // ---- fast path: register sliding window, 5-deep rotation ----
        const float4* e4 = (const float4*)erow;
        const float4* t4 = (const float4*)trow;
        float4 Ee[5], Tt[5];
        // prologue: stream blocks m = fbase .. fbase+3  -> slots 0..3
#pragma unroll
        for (int m = 0; m < 4; ++m) {
            int g = 64 * (fbase + m) - 128 + lane;
            Ee[m] = e4[g];
            Tt[m] = t4[g];
        }
#pragma unroll
        for (int i = 0; i < FR; ++i) {
            // prefetch stream block for frame i+1 (slot (i+4)%5), not needed by frame i
            if (i < FR - 1) {
                int g = 64 * (fbase + i + 4) - 128 + lane;
                Ee[(i + 4) % 5] = e4[g];
                Tt[(i + 4) % 5] = t4[g];
            }
            float s_et = 0.f, s_tt = 0.f, s_ee = 0.f, s_e = 0.f, s_t = 0.f;
#pragma unroll
            for (int k = 0; k < 4; ++k) {
                float4 e = Ee[(i + k) % 5];
                float4 t = Tt[(i + k) % 5];
#pragma unroll
                for (int j = 0; j < 4; ++j) {
                    float w2 = w2v[k][j];
                    float ev = f4c(e, j), tv = f4c(t, j);
                    float we = w2 * ev, wt = w2 * tv;
                    s_et = fmaf(we, tv, s_et);
                    s_tt = fmaf(wt, tv, s_tt);
                    s_ee = fmaf(we, ev, s_ee);
                    s_e += we;
                    s_t += wt;
                }
                if (k == 2) {   // k==2 block == hop f (owned, disjoint cover)
                    pe += (e.x + e.y) + (e.z + e.w);
                    pt += (t.x + t.y) + (t.z + t.w);
                }
            }
            s_et = wave_reduce(s_et);
            s_tt = wave_reduce(s_tt);
            s_ee = wave_reduce(s_ee);
            s_e  = wave_reduce(s_e);
            s_t  = wave_reduce(s_t);
            if (lane == 0) {
                float* p = ws_part + (size_t)(b * NF + fbase + i) * 5;
                p[0] = s_et; p[1] = s_tt; p[2] = s_ee; p[3] = s_e; p[4] = s_t;
            }
        }
    } else {
        // ---- edge path: scalar loads with reflect mapping (2 waves/row) ----
        for (int i = 0; i < nfr; ++i) {
            int f = fbase + i;
            float s_et = 0.f, s_tt = 0.f, s_ee = 0.f, s_e = 0.f, s_t = 0.f;
#pragma unroll
            for (int k = 0; k < 4; ++k)
#pragma unroll
                for (int j = 0; j < 4; ++j) {
                    int s = 256 * f - 512 + 256 * k + 4 * lane + j;
                    int idx = s < 0 ? -s : (s >= TLEN ? 2 * (TLEN - 1) - s : s);
                    float ev = erow[idx], tv = trow[idx];
                    float w2 = w2v[k][j];
                    float we = w2 * ev, wt = w2 * tv;
                    s_et = fmaf(we, tv, s_et);
                    s_tt = fmaf(wt, tv, s_tt);
                    s_ee = fmaf(we, ev, s_ee);
                    s_e += we;
                    s_t += wt;
                    if (k == 2 && f <= 1874) { pe += ev; pt += tv; }
                }
            s_et = wave_reduce(s_et);
            s_tt = wave_reduce(s_tt);
            s_ee = wave_reduce(s_ee);
            s_e  = wave_reduce(s_e);
            s_t  = wave_reduce(s_t);
            if (lane == 0) {
                float* p = ws_part + (size_t)(b * NF + f) * 5;
                p[0] = s_et; p[1] = s_tt; p[2] = s_ee; p[3] = s_e; p[4] = s_t;
            }
        }
    }

    // per-wave plain-sum partials -> workspace (for the row means)
    pe = wave_reduce(pe);
    pt = wave_reduce(pt);
    if (lane == 0) {
        ws_bs[(0 * NB + b) * WPR + wv] = pe;
        ws_bs[(1 * NB + b) * WPR + wv] = pt;
    }
}

// ---------------- kernel 2: reduce wave sums -> per-row means -------------
__global__ void seg_means(const float* __restrict__ ws_bs, float* __restrict__ ws_mean)
{
    int t = threadIdx.x;             // 256 threads, 1 block: 4 lanes per (sig,row)
    int pair = t >> 2, sub = t & 3;
    const float* p = ws_bs + pair * WPR;
    float s = 0.f;
    for (int c = sub; c < WPR; c += 4) s += p[c];
    s += __shfl_xor(s, 1);
    s += __shfl_xor(s, 2);
    if (sub == 0) ws_mean[pair] = s * (1.0f / (float)TLEN);
}

// ---------------- kernel 3: combine partials + means -> loss --------------
__global__ __launch_bounds__(WTHREADS) void seg_final(
    const float* __restrict__ ws_part, const float* __restrict__ ws_mean,
    float* __restrict__ out)
{
    int idx = blockIdx.x * WTHREADS + threadIdx.x;
    if (idx >= NB * NF) return;
    int b = idx / NF;
    const float* p = ws_part + (size_t)idx * 5;
    float me = ws_mean[b];
    float mt = ws_mean[NB + b];
    float S_et = p[0], S_tt = p[1], S_ee = p[2], S_e = p[3], S_t = p[4];
    const float W2 = 384.0f;         // sum of squared periodic Hann, exact

    float dot = S_et - mt * S_e - me * S_t + me * mt * W2;
    float tt  = S_tt - 2.0f * mt * S_t + mt * mt * W2;
    float ee  = S_ee - 2.0f * me * S_e + me * me * W2;

    float a     = dot / (tt + 1e-8f);
    float st2   = a * a * tt;
    float en2   = ee - 2.0f * a * dot + st2;
    float ratio = st2 / (en2 + 1e-8f);
    out[idx] = -10.0f * log10f(ratio + 1e-8f);
}

extern "C" void kernel_launch(void* const* d_in, const int* in_sizes, int n_in,
                              void* d_out, int out_size, void* d_ws, size_t ws_size,
                              hipStream_t stream)
{
    const float* est = (const float*)d_in[0];
    const float* tgt = (const float*)d_in[1];
    float* out = (float*)d_out;

    float* ws      = (float*)d_ws;
    float* ws_part = ws;                                   // NB*NF*5   floats
    float* ws_bs   = ws_part + (size_t)NB * NF * 5;        // 2*NB*WPR  floats
    float* ws_mean = ws_bs + 2 * NB * WPR;                 // 2*NB      floats

    dim3 grid1((WPR + 3) / 4, NB);
    seg_frames<<<grid1, WTHREADS, 0, stream>>>(est, tgt, ws_part, ws_bs);
    seg_means<<<1, WTHREADS, 0, stream>>>(ws_bs, ws_mean);
    dim3 grid3((NB * NF + WTHREADS - 1) / WTHREADS);
    seg_final<<<grid3, WTHREADS, 0, stream>>>(ws_part, ws_mean, out);
}